// Round 16
// baseline (67.782 us; speedup 1.0000x reference)
//
#include <hip/hip_runtime.h>
#include <hip/hip_bf16.h>

// GAT, 2 layers, N=8192 nodes, sparse adjacency (~270K edges incl. self-loops).
// Masked softmax with -1e9 fill == sparse neighbor softmax (exp underflows to 0).
// Round 16: gemm2+f2 FOLDED into attn1's epilogue (the out1 row is already in
// registers there): lanes 0-31 stash fp32 row to LDS orow, all 64 lanes compute
// h2[row][c]=sum_k orow[k]*W2t[c][k] (c=lane&15, k-group=lane>>4, kb-staggered
// conflict-free orow reads), 2 shuffles reduce groups, f2 via 16-wide reduce.
// Deletes: gemm2f2 kernel, out1b buffer (4MB write + 4MB read). Layer 2 now
// consumes fp32 out1 (reference-faithful; was bf16). 5 launches.
// Workspace (~26 MB): h1b[0,4MB); bitmap[16,24MB); tail at 24MB.

#define NN 8192
#define MAXD 128  // weight-phase slots; P(in-degree>128) ~ 1e-18 (Poisson 32)

typedef __bf16 bf16x8 __attribute__((ext_vector_type(8)));
typedef float f32x4 __attribute__((ext_vector_type(4)));
typedef unsigned short u16x8 __attribute__((ext_vector_type(8)));

__device__ __forceinline__ unsigned short f2bf(float f) {
  unsigned u = __float_as_uint(f);
  unsigned r = (u + 0x7fffu + ((u >> 16) & 1u)) >> 16;  // round-nearest-even
  return (unsigned short)r;
}
__device__ __forceinline__ float bf2f(unsigned short u) {
  return __uint_as_float(((unsigned)u) << 16);
}
__device__ __forceinline__ float lrelu02(float e) { return e > 0.f ? e : 0.2f * e; }

// ---------- prep: zero bitmap + f1s/f1d, W1^T bf16, W2^T bf16 ----------
__global__ __launch_bounds__(256) void prep_kernel(uint4* __restrict__ bitmap,
                                                   const float* __restrict__ W1,
                                                   unsigned short* __restrict__ W1t,
                                                   const float* __restrict__ W2,
                                                   unsigned short* __restrict__ W2t,
                                                   float4* __restrict__ f1sd) {
  const int bid = blockIdx.x, tid = threadIdx.x;
  if (bid < 2048) {
    bitmap[bid * 256 + tid] = uint4{0u, 0u, 0u, 0u};
  } else if (bid < 2560) {
    const int gid = (bid - 2048) * 256 + tid;  // 131072 total
    const int n = gid >> 9, k = gid & 511;
    W1t[gid] = f2bf(W1[(size_t)k * 256 + n]);  // W1t[n][k]
  } else if (bid == 2560) {
    for (int i = tid; i < 16 * 256; i += 256) {
      const int n = i >> 8, k = i & 255;
      W2t[i] = f2bf(W2[(size_t)k * 16 + n]);   // W2t[n][k]
    }
  } else {
    // zero f1s[8192] ++ f1d[8192] (contiguous): 4096 float4
    for (int i = tid; i < 4096; i += 256) f1sd[i] = float4{0.f, 0.f, 0.f, 0.f};
  }
}

// ---------- scatter edges into bitmap (dedup via OR) ----------
__global__ void scatter_kernel(const int* __restrict__ ei, int E,
                               unsigned* __restrict__ bitmap) {
  const int t = blockIdx.x * 256 + threadIdx.x;
  if (t >= E) return;
  const int s = ei[t];
  const int d = ei[E + t];
  atomicOr(bitmap + (size_t)s * 256 + (d >> 5), 1u << (d & 31));
}

// ---------- GEMM1 (MFMA) + fused f1: h1b = bf16(x @ W1); f1s/f1d += partials ----------
// 64x64 tile, BK=64, 4 waves; XOR-swizzled LDS (round-10 verified: write-side
// conflict-free, read 2-way=free; A/B share map -> k-perm cancels). grid
// (128,4): bn-siblings of one bm share an XCD (dispatch idx = y*128+x, 128%8==0)
// so the X row-panel is read from L3 once and L2-hit 3x.
__global__ __launch_bounds__(256) void gemm1_mfma_kernel(
    const float* __restrict__ X, const unsigned short* __restrict__ W1t,
    unsigned short* __restrict__ h1b, const float* __restrict__ A1S,
    const float* __restrict__ A1D, float* __restrict__ f1s, float* __restrict__ f1d) {
  constexpr int K = 512;
  __shared__ __align__(16) unsigned short lds[1024 * 8];  // 512 A + 512 B units = 16 KB
  const int t = threadIdx.x;
  const int w = t >> 6, l = t & 63;
  const int lr = l & 15, lg = l >> 4;
  const int bm = blockIdx.x * 64, bn = blockIdx.y * 64;
  const int r8 = t >> 3, c8 = t & 7;  // staging coords: row r8(+32), 16B k-chunk c8

  f32x4 acc[4];
  const f32x4 fz = {0.f, 0.f, 0.f, 0.f};
#pragma unroll
  for (int cb = 0; cb < 4; ++cb) acc[cb] = fz;

  for (int k0 = 0; k0 < K; k0 += 64) {
    float4 xa[2][2];
#pragma unroll
    for (int p = 0; p < 2; ++p) {
      const float* s = X + (size_t)(bm + r8 + p * 32) * K + k0 + c8 * 8;
      xa[p][0] = *(const float4*)s;
      xa[p][1] = *(const float4*)(s + 4);
    }
    uint4 wb[2];
#pragma unroll
    for (int p = 0; p < 2; ++p)
      wb[p] = *(const uint4*)(W1t + (size_t)(bn + r8 + p * 32) * K + k0 + c8 * 8);
    __syncthreads();  // prev tile's LDS reads done
#pragma unroll
    for (int p = 0; p < 2; ++p) {
      const int row = r8 + p * 32;
      const int u = ((row >> 4) << 7) + ((c8 >> 2) << 6) + ((c8 & 3) << 4) + ((row & 15) ^ c8);
      u16x8 v;
      v[0] = f2bf(xa[p][0].x); v[1] = f2bf(xa[p][0].y);
      v[2] = f2bf(xa[p][0].z); v[3] = f2bf(xa[p][0].w);
      v[4] = f2bf(xa[p][1].x); v[5] = f2bf(xa[p][1].y);
      v[6] = f2bf(xa[p][1].z); v[7] = f2bf(xa[p][1].w);
      *(u16x8*)(lds + u * 8) = v;
    }
#pragma unroll
    for (int p = 0; p < 2; ++p) {
      const int row = r8 + p * 32;
      const int u = 512 + ((row >> 4) << 7) + ((c8 >> 2) << 6) + ((c8 & 3) << 4) + ((row & 15) ^ c8);
      *(uint4*)(lds + u * 8) = wb[p];
    }
    __syncthreads();
#pragma unroll
    for (int ks = 0; ks < 2; ++ks) {
      const int xr = lr ^ (ks * 4 + lg);
      const bf16x8 a = *(const bf16x8*)(lds + ((w << 7) + (ks << 6) + (lg << 4) + xr) * 8);
      const bf16x8 b0 = *(const bf16x8*)(lds + (512 + (0 << 7) + (ks << 6) + (lg << 4) + xr) * 8);
      const bf16x8 b1 = *(const bf16x8*)(lds + (512 + (1 << 7) + (ks << 6) + (lg << 4) + xr) * 8);
      const bf16x8 b2 = *(const bf16x8*)(lds + (512 + (2 << 7) + (ks << 6) + (lg << 4) + xr) * 8);
      const bf16x8 b3 = *(const bf16x8*)(lds + (512 + (3 << 7) + (ks << 6) + (lg << 4) + xr) * 8);
      acc[0] = __builtin_amdgcn_mfma_f32_16x16x32_bf16(a, b0, acc[0], 0, 0, 0);
      acc[1] = __builtin_amdgcn_mfma_f32_16x16x32_bf16(a, b1, acc[1], 0, 0, 0);
      acc[2] = __builtin_amdgcn_mfma_f32_16x16x32_bf16(a, b2, acc[2], 0, 0, 0);
      acc[3] = __builtin_amdgcn_mfma_f32_16x16x32_bf16(a, b3, acc[3], 0, 0, 0);
    }
  }
  // ---- C-write; C/D layout: row=(l>>4)*4+q, col=l&15 (m89-verified) ----
#pragma unroll
  for (int cb = 0; cb < 4; ++cb)
#pragma unroll
    for (int q = 0; q < 4; ++q) {
      const int row = bm + w * 16 + lg * 4 + q;
      h1b[(size_t)row * 256 + bn + cb * 16 + lr] = f2bf(acc[cb][q]);
    }
  // ---- fused f1: partial dots over this tile's 64 cols, atomicAdd per row ----
  float a1sv[4], a1dv[4];
#pragma unroll
  for (int cb = 0; cb < 4; ++cb) {
    a1sv[cb] = A1S[bn + cb * 16 + lr];
    a1dv[cb] = A1D[bn + cb * 16 + lr];
  }
#pragma unroll
  for (int q = 0; q < 4; ++q) {
    float ps = 0.f, pd = 0.f;
#pragma unroll
    for (int cb = 0; cb < 4; ++cb) {
      ps = fmaf(acc[cb][q], a1sv[cb], ps);
      pd = fmaf(acc[cb][q], a1dv[cb], pd);
    }
#pragma unroll
    for (int off = 8; off; off >>= 1) {
      ps += __shfl_xor(ps, off, 16);
      pd += __shfl_xor(pd, off, 16);
    }
    if (lr == 0) {
      const int row = bm + w * 16 + lg * 4 + q;
      atomicAdd(f1s + row, ps);
      atomicAdd(f1d + row, pd);
    }
  }
}

// ---------- layer-1 attention + in-wave CSR build + fused layer-2 GEMM/f2 ----------
// Per wave: (1) CSR build from own bitmap row (popc+scan -> LDS; persist ushort
// list + deg for attn2); (2) parallel softmax weights; (3) gather out1 row =
// attn @ h1b (fp32, 16B/lane, halves-split); (4) ELU; (5) stash fp32 row in
// LDS orow and compute h2[row] = out1row @ W2 + f2 dots (replaces gemm2f2).
__global__ __launch_bounds__(256) void attn1_kernel(unsigned* __restrict__ bitmap,
                                                    int* __restrict__ degarr,
                                                    const unsigned short* __restrict__ h1b,
                                                    const float* __restrict__ fs,
                                                    const float* __restrict__ fd,
                                                    const unsigned short* __restrict__ W2t,
                                                    const float* __restrict__ a2s,
                                                    const float* __restrict__ a2d,
                                                    float* __restrict__ h2,
                                                    float* __restrict__ f2s,
                                                    float* __restrict__ f2d) {
  __shared__ float wsh[4][MAXD];
  __shared__ int jsh[4][MAXD];
  __shared__ __align__(16) float orow[4][256];
  const int lane = threadIdx.x & 63;
  const int wv = threadIdx.x >> 6;
  const int row = blockIdx.x * 4 + wv;
  unsigned* brow = bitmap + (size_t)row * 256;
  // ---- in-wave CSR build ----
  const uint4 wq = *(const uint4*)(brow + lane * 4);
  const int cnt = __popc(wq.x) + __popc(wq.y) + __popc(wq.z) + __popc(wq.w);
  int inc = cnt;
#pragma unroll
  for (int d = 1; d < 64; d <<= 1) {
    const int t2 = __shfl_up(inc, d);
    if (lane >= d) inc += t2;
  }
  int off = inc - cnt;  // exclusive prefix
  const int deg = __shfl(inc, 63);
  {
    const unsigned words[4] = {wq.x, wq.y, wq.z, wq.w};
    const int base_j = lane * 128;
#pragma unroll
    for (int q = 0; q < 4; ++q) {
      unsigned word = words[q];
      while (word) {
        const int b = __ffs(word) - 1;
        word &= word - 1;
        jsh[wv][off++] = base_j + q * 32 + b;
      }
    }
  }
  if (lane == 0) degarr[row] = deg;
  // persist ushort list for attn2 (in-place; row already consumed into regs)
  {
    unsigned short* nbp = (unsigned short*)brow;
    if (lane < deg) nbp[lane] = (unsigned short)jsh[wv][lane];
    if (lane + 64 < deg) nbp[lane + 64] = (unsigned short)jsh[wv][lane + 64];
  }
  const float fsr = fs[row];
  // ---- weight phase: lane k handles neighbors k and k+64 (from LDS) ----
  const int j0 = (lane < deg) ? jsh[wv][lane] : 0;
  const int j1 = (lane + 64 < deg) ? jsh[wv][lane + 64] : 0;
  const float e0 = (lane < deg) ? lrelu02(fsr + fd[j0]) : -1e30f;
  const float e1 = (lane + 64 < deg) ? lrelu02(fsr + fd[j1]) : -1e30f;
  float m = fmaxf(e0, e1);
#pragma unroll
  for (int off2 = 32; off2; off2 >>= 1) m = fmaxf(m, __shfl_xor(m, off2));
  const float w0 = (lane < deg) ? expf(e0 - m) : 0.f;
  const float w1 = (lane + 64 < deg) ? expf(e1 - m) : 0.f;
  float s = w0 + w1;
#pragma unroll
  for (int off2 = 32; off2; off2 >>= 1) s += __shfl_xor(s, off2);
  wsh[wv][lane] = w0;
  wsh[wv][lane + 64] = w1;
  // same-wave LDS produce->consume; compiler inserts lgkmcnt
  // ---- gather: halves of the wave take alternating neighbors; 16B per lane ----
  const int half = lane >> 5, lh = lane & 31;
  float acc[8] = {0.f, 0.f, 0.f, 0.f, 0.f, 0.f, 0.f, 0.f};
  int t = 0;
  for (; t + 8 <= deg; t += 8) {  // 4 pairs -> 4 independent 16B loads in flight
    const int ja = jsh[wv][t + half], jb = jsh[wv][t + 2 + half];
    const int jc = jsh[wv][t + 4 + half], jd = jsh[wv][t + 6 + half];
    const float Wa = wsh[wv][t + half], Wb = wsh[wv][t + 2 + half];
    const float Wc = wsh[wv][t + 4 + half], Wd = wsh[wv][t + 6 + half];
    const u16x8 va = *(const u16x8*)(h1b + (size_t)ja * 256 + lh * 8);
    const u16x8 vb = *(const u16x8*)(h1b + (size_t)jb * 256 + lh * 8);
    const u16x8 vc = *(const u16x8*)(h1b + (size_t)jc * 256 + lh * 8);
    const u16x8 vd = *(const u16x8*)(h1b + (size_t)jd * 256 + lh * 8);
#pragma unroll
    for (int e = 0; e < 8; ++e)
      acc[e] = fmaf(Wa, bf2f(va[e]),
               fmaf(Wb, bf2f(vb[e]), fmaf(Wc, bf2f(vc[e]), fmaf(Wd, bf2f(vd[e]), acc[e]))));
  }
  for (; t < deg; t += 2) {  // tail pairs (odd tail: half 1 gets weight 0)
    const int idx = t + half;
    const int jt = (idx < deg) ? jsh[wv][idx] : 0;
    const float Wt = (idx < deg) ? wsh[wv][idx] : 0.f;
    const u16x8 v = *(const u16x8*)(h1b + (size_t)jt * 256 + lh * 8);
#pragma unroll
    for (int e = 0; e < 8; ++e) acc[e] = fmaf(Wt, bf2f(v[e]), acc[e]);
  }
  // combine halves; lanes 0-31 hold the fp32 out1 row (8 cols each)
#pragma unroll
  for (int e = 0; e < 8; ++e) acc[e] += __shfl_xor(acc[e], 32);
  const float inv = 1.f / s;
  float ve[8];
#pragma unroll
  for (int e = 0; e < 8; ++e) {
    float v = acc[e] * inv;
    ve[e] = v > 0.f ? v : expf(v) - 1.f;  // elu
  }
  if (lane < 32) {  // stash fp32 row to LDS (same-wave consume below)
    const float4 o0 = {ve[0], ve[1], ve[2], ve[3]};
    const float4 o1 = {ve[4], ve[5], ve[6], ve[7]};
    *(float4*)&orow[wv][lh * 8] = o0;
    *(float4*)&orow[wv][lh * 8 + 4] = o1;
  }
  // ---- fused layer-2 GEMM: h2[row][c] = sum_k orow[k] * W2t[c][k] ----
  // c = lane&15, k-group g = lane>>4 (64 k each); kb staggered by g so the 4
  // groups' float4 reads hit disjoint bank sets {0,8,16,24}+0..3.
  const int c = lane & 15, g = lane >> 4;
  float hsum = 0.f;
#pragma unroll
  for (int kb = 0; kb < 8; ++kb) {
    const int kk = g * 64 + (((kb + g) & 7) << 3);
    const float4 o0 = *(const float4*)&orow[wv][kk];
    const float4 o1 = *(const float4*)&orow[wv][kk + 4];
    const u16x8 w8 = *(const u16x8*)(W2t + (size_t)c * 256 + kk);
    hsum = fmaf(o0.x, bf2f(w8[0]), hsum);
    hsum = fmaf(o0.y, bf2f(w8[1]), hsum);
    hsum = fmaf(o0.z, bf2f(w8[2]), hsum);
    hsum = fmaf(o0.w, bf2f(w8[3]), hsum);
    hsum = fmaf(o1.x, bf2f(w8[4]), hsum);
    hsum = fmaf(o1.y, bf2f(w8[5]), hsum);
    hsum = fmaf(o1.z, bf2f(w8[6]), hsum);
    hsum = fmaf(o1.w, bf2f(w8[7]), hsum);
  }
  hsum += __shfl_xor(hsum, 16);
  hsum += __shfl_xor(hsum, 32);  // all lanes: h2[row][c]
  if (lane < 16) h2[(size_t)row * 16 + c] = hsum;
  // ---- fused f2: fs/fd = h2[row] . a2 (16-wide reduce) ----
  float ss = hsum * a2s[c], dd = hsum * a2d[c];
#pragma unroll
  for (int off2 = 8; off2; off2 >>= 1) {
    ss += __shfl_xor(ss, off2, 16);
    dd += __shfl_xor(dd, off2, 16);
  }
  if (lane == 0) {
    f2s[row] = ss;
    f2d[row] = dd;
  }
}

// ---------- layer-2 attention + final log_softmax over 16 classes ----------
__global__ __launch_bounds__(256) void attn2_kernel(const unsigned* __restrict__ bitmap,
                                                    const int* __restrict__ degarr,
                                                    const float* __restrict__ h2,
                                                    const float* __restrict__ fs,
                                                    const float* __restrict__ fd,
                                                    float* __restrict__ out) {
  __shared__ float wsh[4][MAXD];
  __shared__ int jsh[4][MAXD];
  const int lane = threadIdx.x & 63;
  const int wv = threadIdx.x >> 6;
  const int row = blockIdx.x * 4 + wv;
  const unsigned short* nb = (const unsigned short*)(bitmap + (size_t)row * 256);
  const int deg = degarr[row];
  const float fsr = fs[row];
  const int j0 = (lane < deg) ? (int)nb[lane] : 0;
  const int j1 = (lane + 64 < deg) ? (int)nb[lane + 64] : 0;
  const float e0 = (lane < deg) ? lrelu02(fsr + fd[j0]) : -1e30f;
  const float e1 = (lane + 64 < deg) ? lrelu02(fsr + fd[j1]) : -1e30f;
  float m = fmaxf(e0, e1);
#pragma unroll
  for (int off = 32; off; off >>= 1) m = fmaxf(m, __shfl_xor(m, off));
  const float w0 = (lane < deg) ? expf(e0 - m) : 0.f;
  const float w1 = (lane + 64 < deg) ? expf(e1 - m) : 0.f;
  float s = w0 + w1;
#pragma unroll
  for (int off = 32; off; off >>= 1) s += __shfl_xor(s, off);
  wsh[wv][lane] = w0;
  jsh[wv][lane] = j0;
  wsh[wv][lane + 64] = w1;
  jsh[wv][lane + 64] = j1;
  // ---- gather: 4 neighbors at a time (lane = group*16 + class), x4 in flight ----
  const int c = lane & 15, g = lane >> 4;
  float acc = 0.f;
  int t = g;
  for (; t + 12 < deg; t += 16) {
    const float W0 = wsh[wv][t], W1 = wsh[wv][t + 4];
    const float W2 = wsh[wv][t + 8], W3 = wsh[wv][t + 12];
    const float v0 = h2[(size_t)jsh[wv][t] * 16 + c];
    const float v1 = h2[(size_t)jsh[wv][t + 4] * 16 + c];
    const float v2 = h2[(size_t)jsh[wv][t + 8] * 16 + c];
    const float v3 = h2[(size_t)jsh[wv][t + 12] * 16 + c];
    acc = fmaf(W0, v0, fmaf(W1, v1, fmaf(W2, v2, fmaf(W3, v3, acc))));
  }
  for (; t < deg; t += 4) acc = fmaf(wsh[wv][t], h2[(size_t)jsh[wv][t] * 16 + c], acc);
  acc += __shfl_xor(acc, 16);
  acc += __shfl_xor(acc, 32);
  const float v = acc / s;  // logits
  float mx = v;
#pragma unroll
  for (int off = 8; off; off >>= 1) mx = fmaxf(mx, __shfl_xor(mx, off, 16));
  float se = expf(v - mx);
#pragma unroll
  for (int off = 8; off; off >>= 1) se += __shfl_xor(se, off, 16);
  if (lane < 16) out[(size_t)row * 16 + lane] = v - mx - logf(se);
}

extern "C" void kernel_launch(void* const* d_in, const int* in_sizes, int n_in,
                              void* d_out, int out_size, void* d_ws, size_t ws_size,
                              hipStream_t stream) {
  const float* x = (const float*)d_in[0];
  const int* ei = (const int*)d_in[1];
  const float* W1 = (const float*)d_in[2];
  const float* a1s = (const float*)d_in[3];
  const float* a1d = (const float*)d_in[4];
  const float* W2 = (const float*)d_in[5];
  const float* a2s = (const float*)d_in[6];
  const float* a2d = (const float*)d_in[7];
  float* out = (float*)d_out;
  const int E = in_sizes[1] / 2;

  char* ws = (char*)d_ws;
  unsigned short* h1b = (unsigned short*)ws;           // 4 MB
  unsigned* bitmap = (unsigned*)(ws + (16u << 20));    // 8 MB, reused as CSR
  float* f1s = (float*)(ws + (24u << 20));
  float* f1d = f1s + NN;
  float* h2 = f1d + NN;                                // 512 KB
  float* f2s = h2 + (size_t)NN * 16;
  float* f2d = f2s + NN;
  int* deg = (int*)(f2d + NN);
  unsigned short* w1t = (unsigned short*)(deg + NN);   // 256 KB
  unsigned short* w2t = w1t + (size_t)256 * 512;       // 8 KB

  prep_kernel<<<2562, 256, 0, stream>>>((uint4*)bitmap, W1, w1t, W2, w2t, (float4*)f1s);
  scatter_kernel<<<(E + 255) / 256, 256, 0, stream>>>(ei, E, bitmap);
  gemm1_mfma_kernel<<<dim3(NN / 64, 256 / 64), 256, 0, stream>>>(x, w1t, h1b, a1s, a1d,
                                                                 f1s, f1d);
  attn1_kernel<<<NN / 4, 256, 0, stream>>>(bitmap, deg, h1b, f1s, f1d, w2t, a2s, a2d,
                                           h2, f2s, f2d);
  attn2_kernel<<<NN / 4, 256, 0, stream>>>(bitmap, deg, h2, f2s, f2d, out);
}